// Round 4
// baseline (8258.716 us; speedup 1.0000x reference)
//
#include <hip/hip_runtime.h>
#include <cmath>

namespace {

constexpr int BATCH = 64;
constexpr int NREG  = 49;
constexpr int FEATN = 2048;
constexpr int FHN   = 512;
constexpr int HID   = 512;
constexpr int EMBN  = 512;
constexpr int VOC   = 32000;
constexpr int TSTEPS= 40;
constexpr int G4    = 2048;       // 4*H
constexpr int NVT   = VOC / 128;  // 250 v-tiles for logits
constexpr int NBLK  = 256;        // persistent grid size (== CU count)

typedef short bf16x8 __attribute__((ext_vector_type(8)));
typedef float f32x4  __attribute__((ext_vector_type(4)));

__device__ __forceinline__ float sigm(float x) { return 1.0f / (1.0f + expf(-x)); }

__device__ __forceinline__ unsigned short f2bf(float f) {
  unsigned u = __float_as_uint(f);
  unsigned r = (u + 0x7fffu + ((u >> 16) & 1u)) >> 16;   // RNE
  return (unsigned short)r;
}
__device__ __forceinline__ float bf2f(unsigned short h) {
  return __uint_as_float(((unsigned)h) << 16);
}

__device__ __forceinline__ bool better(float a, int ia, float b, int ib) {
  return a > b || (a == b && ia < ib);
}
__device__ __forceinline__ void top2_merge(float& v1, int& i1, float& v2, int& i2,
                                           float u1, int j1, float u2, int j2) {
  if (better(u1, j1, v1, i1)) {
    float t = v1; int ti = i1;
    v1 = u1; i1 = j1;
    if (better(u2, j2, t, ti)) { v2 = u2; i2 = j2; } else { v2 = t; i2 = ti; }
  } else {
    if (better(u1, j1, v2, i2)) { v2 = u1; i2 = j1; }
  }
}
__device__ __forceinline__ void lse_merge(float& m, float& s, float om, float os) {
  float nm = fmaxf(m, om);
  float ns = 0.f;
  if (m  > -INFINITY) ns += s  * expf(m  - nm);
  if (om > -INFINITY) ns += os * expf(om - nm);
  m = nm; s = ns;
}

// ================= shared-memory union for the persistent kernel =================
struct SmemC {                       // phase C (logits)
  unsigned short hl[32768];          // 64KB h1 tile, XOR-swizzled
  float rm[256], rs[256], rv1[256], rv2[256];
  int   ri1[256], ri2[256];
};
struct SmemAB {                      // phases A/B (lstm)
  float gs[4][64][16];               // [gate][batch][j] 16KB
};
struct SmemD {                       // phase D (sample)
  float rm[256], rs[256], rv1[256], rv2[256];
  int   ri1[256], ri2[256];
  float s1[256], s2[256];
};
union Smem {
  SmemC c; SmemAB ab; SmemD d;
  char pad[86016];                   // 84KB -> max 1 block/CU (160KB LDS) => 256 blocks co-resident
};

// ================= device-scope grid barrier (sense via generation counter) =================
__device__ __forceinline__ void gridbar(unsigned* bar) {
  __syncthreads();
  if (threadIdx.x == 0) {
    __threadfence();
    unsigned g = __hip_atomic_load(bar + 1, __ATOMIC_RELAXED, __HIP_MEMORY_SCOPE_AGENT);
    unsigned a = __hip_atomic_fetch_add(bar, 1u, __ATOMIC_ACQ_REL, __HIP_MEMORY_SCOPE_AGENT);
    if (a == (unsigned)NBLK - 1) {
      __hip_atomic_store(bar, 0u, __ATOMIC_RELAXED, __HIP_MEMORY_SCOPE_AGENT);
      __hip_atomic_fetch_add(bar + 1, 1u, __ATOMIC_RELEASE, __HIP_MEMORY_SCOPE_AGENT);
    } else {
      while (__hip_atomic_load(bar + 1, __ATOMIC_RELAXED, __HIP_MEMORY_SCOPE_AGENT) == g)
        __builtin_amdgcn_s_sleep(1);
    }
    __threadfence();
  }
  __syncthreads();
}

// ================= prep kernels (one-time) =================

__global__ __launch_bounds__(256) void k_trans(const float* __restrict__ src,
    unsigned short* __restrict__ dhi, unsigned short* __restrict__ dlo, int K, int N) {
  __shared__ float tile[32][33];
  const int k0 = blockIdx.x * 32, n0 = blockIdx.y * 32;
  const int tx = threadIdx.x & 31, ty = threadIdx.x >> 5;
#pragma unroll
  for (int r = ty; r < 32; r += 8) tile[r][tx] = src[(size_t)(k0 + r) * N + n0 + tx];
  __syncthreads();
#pragma unroll
  for (int r = ty; r < 32; r += 8) {
    float v = tile[tx][r];
    unsigned short hv = f2bf(v);
    size_t o = (size_t)(n0 + r) * K + k0 + tx;
    dhi[o] = hv;
    dlo[o] = f2bf(v - bf2f(hv));
  }
}

__global__ void k_split(const float* __restrict__ src, unsigned short* __restrict__ dhi,
                        unsigned short* __restrict__ dlo) {
  const size_t i = (size_t)blockIdx.x * 256 + threadIdx.x;
  const float4* p = reinterpret_cast<const float4*>(src) + i * 2;
  float4 a = p[0], b = p[1];
  float v[8] = {a.x, a.y, a.z, a.w, b.x, b.y, b.z, b.w};
  unsigned short hi[8], lo[8];
#pragma unroll
  for (int j = 0; j < 8; ++j) {
    hi[j] = f2bf(v[j]);
    lo[j] = f2bf(v[j] - bf2f(hi[j]));
  }
  uint4 oh, ol;
  oh.x = hi[0] | (hi[1] << 16); oh.y = hi[2] | (hi[3] << 16);
  oh.z = hi[4] | (hi[5] << 16); oh.w = hi[6] | (hi[7] << 16);
  ol.x = lo[0] | (lo[1] << 16); ol.y = lo[2] | (lo[3] << 16);
  ol.z = lo[4] | (lo[5] << 16); ol.w = lo[6] | (lo[7] << 16);
  reinterpret_cast<uint4*>(dhi)[i] = oh;
  reinterpret_cast<uint4*>(dlo)[i] = ol;
}

__global__ void k_emb2bf(const float* __restrict__ emb, unsigned short* __restrict__ ebf) {
  const size_t i = (size_t)blockIdx.x * 256 + threadIdx.x;
  const float4* p = reinterpret_cast<const float4*>(emb) + i * 2;
  float4 a = p[0], b = p[1];
  uint4 o;
  o.x = (unsigned)f2bf(a.x) | ((unsigned)f2bf(a.y) << 16);
  o.y = (unsigned)f2bf(a.z) | ((unsigned)f2bf(a.w) << 16);
  o.z = (unsigned)f2bf(b.x) | ((unsigned)f2bf(b.y) << 16);
  o.w = (unsigned)f2bf(b.z) | ((unsigned)f2bf(b.w) << 16);
  reinterpret_cast<uint4*>(ebf)[i] = o;
}

__global__ __launch_bounds__(256) void k_feat_mfma(
    const unsigned short* __restrict__ Ahi, const unsigned short* __restrict__ Alo,
    const unsigned short* __restrict__ Bhi, const unsigned short* __restrict__ Blo,
    const float* __restrict__ bias, float* __restrict__ femb) {
  const int m0 = blockIdx.x * 64, n0 = blockIdx.y * 64;
  const int tid = threadIdx.x, lane = tid & 63, w = tid >> 6;
  const int l15 = lane & 15, l4 = lane >> 4;
  f32x4 acc[4];
#pragma unroll
  for (int nt = 0; nt < 4; ++nt) acc[nt] = (f32x4){0.f, 0.f, 0.f, 0.f};
  const size_t arow = (size_t)(m0 + w * 16 + l15) * FEATN;
  for (int kk = 0; kk < FEATN / 32; ++kk) {
    const int k = kk * 32 + l4 * 8;
    bf16x8 a1 = *reinterpret_cast<const bf16x8*>(Ahi + arow + k);
    bf16x8 a2 = *reinterpret_cast<const bf16x8*>(Alo + arow + k);
#pragma unroll
    for (int nt = 0; nt < 4; ++nt) {
      const size_t brow = (size_t)(n0 + nt * 16 + l15) * FEATN + k;
      bf16x8 b1 = *reinterpret_cast<const bf16x8*>(Bhi + brow);
      bf16x8 b2 = *reinterpret_cast<const bf16x8*>(Blo + brow);
      acc[nt] = __builtin_amdgcn_mfma_f32_16x16x32_bf16(a1, b1, acc[nt], 0, 0, 0);
      acc[nt] = __builtin_amdgcn_mfma_f32_16x16x32_bf16(a1, b2, acc[nt], 0, 0, 0);
      acc[nt] = __builtin_amdgcn_mfma_f32_16x16x32_bf16(a2, b1, acc[nt], 0, 0, 0);
    }
  }
#pragma unroll
  for (int nt = 0; nt < 4; ++nt)
#pragma unroll
    for (int i = 0; i < 4; ++i) {
      int m = m0 + w * 16 + l4 * 4 + i, n = n0 + nt * 16 + l15;
      femb[(size_t)m * FHN + n] = tanhf(acc[nt][i] + bias[n]);
    }
}

__global__ void k_mean(const float* __restrict__ femb, float* __restrict__ fmean) {
  const int gid = blockIdx.x * 256 + threadIdx.x;  // 32768
  const int b = gid >> 9, f = gid & 511;
  float s = 0.f;
  for (int n = 0; n < NREG; ++n) s += femb[(size_t)(b * NREG + n) * FHN + f];
  fmean[gid] = s * (1.0f / NREG);
}

__global__ __launch_bounds__(256) void k_h0c0(const float* __restrict__ fmean,
    const float* __restrict__ Wc, const float* __restrict__ bc,
    const float* __restrict__ Wh, const float* __restrict__ bh,
    float* __restrict__ hbuf, float* __restrict__ cbuf,
    unsigned short* __restrict__ hshi, unsigned short* __restrict__ hslo) {
  const int n0 = blockIdx.x * 64, l = blockIdx.y, isH = blockIdx.z;
  const float* W   = (isH ? Wh : Wc) + (size_t)l * FHN * HID;
  const float* bias= (isH ? bh : bc) + l * HID;
  float* outp      = (isH ? hbuf : cbuf) + (size_t)l * BATCH * HID;
  __shared__ float As[16][68], Bs[16][68];
  const int tid = threadIdx.x, tx = tid & 15, ty = tid >> 4;
  float acc[4][4] = {};
  for (int k0 = 0; k0 < FHN; k0 += 16) {
#pragma unroll
    for (int e = 0; e < 4; ++e) { int idx = tid + e * 256, m = idx >> 4, k = idx & 15; As[k][m] = fmean[m * FHN + k0 + k]; }
#pragma unroll
    for (int e = 0; e < 4; ++e) { int idx = tid + e * 256, k = idx >> 6, n = idx & 63; Bs[k][n] = W[(size_t)(k0 + k) * HID + n0 + n]; }
    __syncthreads();
#pragma unroll
    for (int k = 0; k < 16; ++k) {
      float4 av = *(const float4*)&As[k][ty * 4];
      float4 bv = *(const float4*)&Bs[k][tx * 4];
      float a[4] = {av.x, av.y, av.z, av.w}, b[4] = {bv.x, bv.y, bv.z, bv.w};
#pragma unroll
      for (int i = 0; i < 4; ++i)
#pragma unroll
        for (int j = 0; j < 4; ++j) acc[i][j] = fmaf(a[i], b[j], acc[i][j]);
    }
    __syncthreads();
  }
#pragma unroll
  for (int i = 0; i < 4; ++i) {
    int m = ty * 4 + i, n = n0 + tx * 4;
    float vals[4];
#pragma unroll
    for (int j = 0; j < 4; ++j) vals[j] = acc[i][j] + bias[n + j];
    *(float4*)&outp[(size_t)m * HID + n] = make_float4(vals[0], vals[1], vals[2], vals[3]);
    if (isH) {
#pragma unroll
      for (int j = 0; j < 4; ++j) {
        unsigned short hv = f2bf(vals[j]);
        size_t o = (size_t)l * BATCH * HID + (size_t)m * HID + n + j;  // parity-0 slot
        hshi[o] = hv;
        hslo[o] = f2bf(vals[j] - bf2f(hv));
      }
    }
  }
}

__global__ void k_initx(unsigned short* __restrict__ xhi, unsigned short* __restrict__ xlo) {
  const int i = blockIdx.x * 256 + threadIdx.x;
  xhi[i] = 0x4040; xlo[i] = 0;      // 3.0 exact in bf16
}

__global__ void k_zero(unsigned* __restrict__ bar) {
  if (threadIdx.x < 8) bar[threadIdx.x] = 0;
}

// ================= persistent-kernel phase bodies =================

// ---- LSTM layer (gates bf16x3 MFMA + fused cell); active on blocks 0..31 ----
__device__ __forceinline__ void lstm_block(int l, int blk, int tid,
    const unsigned short* __restrict__ xh, const unsigned short* __restrict__ xl,
    const unsigned short* __restrict__ hh, const unsigned short* __restrict__ hlo_,
    const unsigned short* __restrict__ wg, const float* __restrict__ bl,
    float* __restrict__ hbuf, float* __restrict__ cbuf,
    unsigned short* __restrict__ ho_hi, unsigned short* __restrict__ ho_lo,
    Smem& sm) {
  const int lane = tid & 63, g = tid >> 6;     // wave == gate (i,f,g,o)
  const int l15 = lane & 15, l4 = lane >> 4;
  const size_t WGM = (size_t)G4 * 512;
  const unsigned short* wih_hi = wg + (((size_t)l * 2 + 0) * 2 + 0) * WGM;
  const unsigned short* wih_lo = wih_hi + WGM;
  const unsigned short* whh_hi = wg + (((size_t)l * 2 + 1) * 2 + 0) * WGM;
  const unsigned short* whh_lo = whh_hi + WGM;
  const size_t nrow = (size_t)(g * 512 + blk * 16 + l15) * 512;
  f32x4 acc[4];
#pragma unroll
  for (int mt = 0; mt < 4; ++mt) acc[mt] = (f32x4){0.f, 0.f, 0.f, 0.f};
#pragma unroll
  for (int kk = 0; kk < 16; ++kk) {          // x @ Wih
    const int k = kk * 32 + l4 * 8;
    bf16x8 b1 = *reinterpret_cast<const bf16x8*>(wih_hi + nrow + k);
    bf16x8 b2 = *reinterpret_cast<const bf16x8*>(wih_lo + nrow + k);
#pragma unroll
    for (int mt = 0; mt < 4; ++mt) {
      const size_t ar = (size_t)(mt * 16 + l15) * 512 + k;
      bf16x8 a1 = *reinterpret_cast<const bf16x8*>(xh + ar);
      bf16x8 a2 = *reinterpret_cast<const bf16x8*>(xl + ar);
      acc[mt] = __builtin_amdgcn_mfma_f32_16x16x32_bf16(a1, b1, acc[mt], 0, 0, 0);
      acc[mt] = __builtin_amdgcn_mfma_f32_16x16x32_bf16(a1, b2, acc[mt], 0, 0, 0);
      acc[mt] = __builtin_amdgcn_mfma_f32_16x16x32_bf16(a2, b1, acc[mt], 0, 0, 0);
    }
  }
#pragma unroll
  for (int kk = 0; kk < 16; ++kk) {          // h @ Whh
    const int k = kk * 32 + l4 * 8;
    bf16x8 b1 = *reinterpret_cast<const bf16x8*>(whh_hi + nrow + k);
    bf16x8 b2 = *reinterpret_cast<const bf16x8*>(whh_lo + nrow + k);
#pragma unroll
    for (int mt = 0; mt < 4; ++mt) {
      const size_t ar = (size_t)(mt * 16 + l15) * 512 + k;
      bf16x8 a1 = *reinterpret_cast<const bf16x8*>(hh + ar);
      bf16x8 a2 = *reinterpret_cast<const bf16x8*>(hlo_ + ar);
      acc[mt] = __builtin_amdgcn_mfma_f32_16x16x32_bf16(a1, b1, acc[mt], 0, 0, 0);
      acc[mt] = __builtin_amdgcn_mfma_f32_16x16x32_bf16(a1, b2, acc[mt], 0, 0, 0);
      acc[mt] = __builtin_amdgcn_mfma_f32_16x16x32_bf16(a2, b1, acc[mt], 0, 0, 0);
    }
  }
#pragma unroll
  for (int mt = 0; mt < 4; ++mt)
#pragma unroll
    for (int i = 0; i < 4; ++i)
      sm.ab.gs[g][mt * 16 + l4 * 4 + i][l15] = acc[mt][i];
  __syncthreads();
#pragma unroll
  for (int e = 0; e < 4; ++e) {
    const int idx = tid * 4 + e;             // 1024 cells / 256 threads
    const int b = idx >> 4, jj = idx & 15, j = blk * 16 + jj;
    float gi = sm.ab.gs[0][b][jj] + bl[l * 2048 + j];
    float gf = sm.ab.gs[1][b][jj] + bl[l * 2048 + 512 + j];
    float gg = sm.ab.gs[2][b][jj] + bl[l * 2048 + 1024 + j];
    float go = sm.ab.gs[3][b][jj] + bl[l * 2048 + 1536 + j];
    const size_t o = (size_t)l * BATCH * HID + (size_t)b * HID + j;
    float cn = sigm(gf) * cbuf[o] + sigm(gi) * tanhf(gg);
    float hn = sigm(go) * tanhf(cn);
    cbuf[o] = cn; hbuf[o] = hn;
    unsigned short hv = f2bf(hn);
    const size_t oh = (size_t)b * HID + j;
    ho_hi[oh] = hv; ho_lo[oh] = f2bf(hn - bf2f(hv));
  }
}

// ---- logits tile (blocks 0..249) ----
__device__ __forceinline__ void logits_block(int blk, int tid,
    const unsigned short* __restrict__ embbf, const unsigned short* __restrict__ h1hi,
    const float* __restrict__ gum_t, float* __restrict__ red, Smem& sm) {
  const int v0 = blk * 128;
  const int lane = tid & 63, w = tid >> 6;
  const int l15 = lane & 15, l4 = lane >> 4;
#pragma unroll
  for (int i = 0; i < 16; ++i) {             // stage h1(hi) -> LDS, XOR swizzle
    int c = tid + i * 256;
    int row = c >> 6;
    int inb = (c & 63) << 4;
    uint4 v = *reinterpret_cast<const uint4*>(h1hi + ((size_t)c << 3));
    int sw = inb ^ ((row & 7) << 4);
    *reinterpret_cast<uint4*>(reinterpret_cast<char*>(sm.c.hl) + row * 1024 + sw) = v;
  }
  __syncthreads();

  f32x4 acc[2][4];
#pragma unroll
  for (int m = 0; m < 2; ++m)
#pragma unroll
    for (int n = 0; n < 4; ++n) acc[m][n] = (f32x4){0.f, 0.f, 0.f, 0.f};

  const unsigned short* aptr = embbf + (size_t)(v0 + w * 32 + l15) * 512 + l4 * 8;
#pragma unroll
  for (int ks = 0; ks < 16; ++ks) {
    bf16x8 a0 = *reinterpret_cast<const bf16x8*>(aptr + ks * 32);
    bf16x8 a1 = *reinterpret_cast<const bf16x8*>(aptr + 16 * 512 + ks * 32);
    bf16x8 bb[4];
#pragma unroll
    for (int n = 0; n < 4; ++n) {
      int row = n * 16 + l15;
      int inb = ks * 64 + l4 * 16;
      int sw = inb ^ ((row & 7) << 4);
      bb[n] = *reinterpret_cast<const bf16x8*>(reinterpret_cast<const char*>(sm.c.hl) + row * 1024 + sw);
    }
#pragma unroll
    for (int n = 0; n < 4; ++n) {
      acc[0][n] = __builtin_amdgcn_mfma_f32_16x16x32_bf16(a0, bb[n], acc[0][n], 0, 0, 0);
      acc[1][n] = __builtin_amdgcn_mfma_f32_16x16x32_bf16(a1, bb[n], acc[1][n], 0, 0, 0);
    }
  }

  const int vb = v0 + w * 32 + l4 * 4;
#pragma unroll
  for (int n = 0; n < 4; ++n) {
    const int b = n * 16 + l15;
    const float* gb = gum_t + (size_t)b * VOC + vb;
    float4 g0 = *reinterpret_cast<const float4*>(gb);
    float4 g1 = *reinterpret_cast<const float4*>(gb + 16);
    float lg[8] = {acc[0][n][0], acc[0][n][1], acc[0][n][2], acc[0][n][3],
                   acc[1][n][0], acc[1][n][1], acc[1][n][2], acc[1][n][3]};
    float gv[8] = {g0.x, g0.y, g0.z, g0.w, g1.x, g1.y, g1.z, g1.w};
    float mx = lg[0];
#pragma unroll
    for (int i = 1; i < 8; ++i) mx = fmaxf(mx, lg[i]);
    float ss = 0.f;
    float v1 = -INFINITY, v2 = -INFINITY; int i1 = 0x7fffffff, i2 = 0x7fffffff;
#pragma unroll
    for (int i = 0; i < 8; ++i) {
      ss += expf(lg[i] - mx);
      float val = lg[i] + gv[i];
      int idx = vb + (i & 3) + ((i >> 2) << 4);
      if (better(val, idx, v1, i1)) { v2 = v1; i2 = i1; v1 = val; i1 = idx; }
      else if (better(val, idx, v2, i2)) { v2 = val; i2 = idx; }
    }
#pragma unroll
    for (int mask = 16; mask <= 32; mask <<= 1) {
      float om = __shfl_xor(mx, mask);
      float os = __shfl_xor(ss, mask);
      float u1 = __shfl_xor(v1, mask); int j1 = __shfl_xor(i1, mask);
      float u2 = __shfl_xor(v2, mask); int j2 = __shfl_xor(i2, mask);
      lse_merge(mx, ss, om, os);
      top2_merge(v1, i1, v2, i2, u1, j1, u2, j2);
    }
    if (lane < 16) {
      int slot = (w * 4 + n) * 16 + l15;
      sm.c.rm[slot] = mx; sm.c.rs[slot] = ss;
      sm.c.rv1[slot] = v1; sm.c.ri1[slot] = i1; sm.c.rv2[slot] = v2; sm.c.ri2[slot] = i2;
    }
  }
  __syncthreads();
  if (tid < 64) {
    const int n = tid >> 4, c = tid & 15;
    int s0 = n * 16 + c;
    float M = sm.c.rm[s0], S = sm.c.rs[s0], V1 = sm.c.rv1[s0], V2 = sm.c.rv2[s0];
    int I1 = sm.c.ri1[s0], I2 = sm.c.ri2[s0];
#pragma unroll
    for (int ww = 1; ww < 4; ++ww) {
      int sl = (ww * 4 + n) * 16 + c;
      lse_merge(M, S, sm.c.rm[sl], sm.c.rs[sl]);
      top2_merge(V1, I1, V2, I2, sm.c.rv1[sl], sm.c.ri1[sl], sm.c.rv2[sl], sm.c.ri2[sl]);
    }
    float* rp = red + ((size_t)blk * 64 + tid) * 8;
    rp[0] = M; rp[1] = S;
    rp[2] = V1; rp[3] = __int_as_float(I1);
    rp[4] = V2; rp[5] = __int_as_float(I2);
  }
}

// ---- final reduce + exact f32 rescore + sample (blocks 0..63) ----
__device__ __forceinline__ void sample_block(int b, int tid, int t,
    const float* __restrict__ red, const float* __restrict__ emb,
    const float* __restrict__ h1f, const float* __restrict__ gum_t,
    unsigned short* __restrict__ xhi, unsigned short* __restrict__ xlo,
    float* __restrict__ out, Smem& sm) {
  float m = -INFINITY, s = 0.f, v1 = -INFINITY, v2 = -INFINITY;
  int i1 = 0x7fffffff, i2 = 0x7fffffff;
  if (tid < NVT) {
    const float* rp = red + ((size_t)tid * 64 + b) * 8;
    m = rp[0]; s = rp[1];
    v1 = rp[2]; i1 = __float_as_int(rp[3]);
    v2 = rp[4]; i2 = __float_as_int(rp[5]);
  }
  sm.d.rm[tid] = m; sm.d.rs[tid] = s;
  sm.d.rv1[tid] = v1; sm.d.ri1[tid] = i1; sm.d.rv2[tid] = v2; sm.d.ri2[tid] = i2;
  __syncthreads();
  for (int off = 128; off > 0; off >>= 1) {
    if (tid < off) {
      float M = sm.d.rm[tid], S = sm.d.rs[tid];
      lse_merge(M, S, sm.d.rm[tid + off], sm.d.rs[tid + off]);
      sm.d.rm[tid] = M; sm.d.rs[tid] = S;
      float a1 = sm.d.rv1[tid], a2 = sm.d.rv2[tid]; int c1 = sm.d.ri1[tid], c2 = sm.d.ri2[tid];
      top2_merge(a1, c1, a2, c2, sm.d.rv1[tid + off], sm.d.ri1[tid + off],
                 sm.d.rv2[tid + off], sm.d.ri2[tid + off]);
      sm.d.rv1[tid] = a1; sm.d.ri1[tid] = c1; sm.d.rv2[tid] = a2; sm.d.ri2[tid] = c2;
    }
    __syncthreads();
  }
  const int I1 = sm.d.ri1[0], I2 = sm.d.ri2[0];
  const float lse = sm.d.rm[0] + logf(sm.d.rs[0]);
  const float* e1 = emb + (size_t)I1 * EMBN;
  const float* e2 = emb + (size_t)I2 * EMBN;
  const float* hb = h1f + b * EMBN;
  float d1 = 0.f, d2 = 0.f;
  for (int k = tid; k < EMBN; k += 256) {
    float hv = hb[k];
    d1 = fmaf(e1[k], hv, d1);
    d2 = fmaf(e2[k], hv, d2);
  }
  sm.d.s1[tid] = d1; sm.d.s2[tid] = d2;
  __syncthreads();
  for (int off = 128; off > 0; off >>= 1) {
    if (tid < off) { sm.d.s1[tid] += sm.d.s1[tid + off]; sm.d.s2[tid] += sm.d.s2[tid + off]; }
    __syncthreads();
  }
  const float x1 = sm.d.s1[0] + gum_t[(size_t)b * VOC + I1];
  const float x2 = sm.d.s2[0] + gum_t[(size_t)b * VOC + I2];
  int tok; float dsel;
  if (x2 > x1 || (x2 == x1 && I2 < I1)) { tok = I2; dsel = sm.d.s2[0]; }
  else                                  { tok = I1; dsel = sm.d.s1[0]; }
  const float* et = emb + (size_t)tok * EMBN;
  for (int k = tid; k < EMBN; k += 256) {
    float ev = et[k];
    unsigned short hv = f2bf(ev);
    xhi[b * EMBN + k] = hv;
    xlo[b * EMBN + k] = f2bf(ev - bf2f(hv));
  }
  if (tid == 0) {
    out[b * TSTEPS + t] = (float)tok;
    out[BATCH * TSTEPS + b * TSTEPS + t] = dsel - lse;
  }
}

// ================= the persistent decode kernel =================
__global__ __launch_bounds__(256, 1) void k_persist(
    const unsigned short* __restrict__ embbf, const float* __restrict__ emb,
    const float* __restrict__ gum, const unsigned short* __restrict__ wg,
    const float* __restrict__ b_l, float* __restrict__ hbuf, float* __restrict__ cbuf,
    unsigned short* __restrict__ xhi, unsigned short* __restrict__ xlo,
    unsigned short* __restrict__ hshi, unsigned short* __restrict__ hslo,
    float* __restrict__ red, float* __restrict__ out, unsigned* __restrict__ bar) {
  __shared__ Smem sm;
  const int blk = blockIdx.x, tid = threadIdx.x;
  const size_t HS = (size_t)BATCH * HID;   // 32768 per (parity,layer) slot

  for (int t = 0; t < TSTEPS; ++t) {
    const float* gum_t = gum + (size_t)t * BATCH * VOC;
    const int p = t & 1, q = p ^ 1;
    // ---- phase A: layer 0 (reads x, h0[p]; writes h0[q]) ----
    if (blk < 32) {
      lstm_block(0, blk, tid, xhi, xlo,
                 hshi + ((size_t)p * 2 + 0) * HS, hslo + ((size_t)p * 2 + 0) * HS,
                 wg, b_l, hbuf, cbuf,
                 hshi + ((size_t)q * 2 + 0) * HS, hslo + ((size_t)q * 2 + 0) * HS, sm);
    } else {
      float s = 0.f;                               // prefetch this step's gumbel HBM->L2/L3
      const float4* gp = reinterpret_cast<const float4*>(gum_t);
      for (unsigned i = (unsigned)(blk - 32) * 256 + tid; i < 512000u; i += 224u * 256u) {
        float4 v = gp[i]; s += v.x + v.y + v.z + v.w;
      }
      asm volatile("" :: "v"(s));
    }
    gridbar(bar);
    // ---- phase B: layer 1 (reads h0[q] as x, h1[p]; writes h1[q]) ----
    if (blk < 32) {
      lstm_block(1, blk, tid,
                 hshi + ((size_t)q * 2 + 0) * HS, hslo + ((size_t)q * 2 + 0) * HS,
                 hshi + ((size_t)p * 2 + 1) * HS, hslo + ((size_t)p * 2 + 1) * HS,
                 wg, b_l, hbuf, cbuf,
                 hshi + ((size_t)q * 2 + 1) * HS, hslo + ((size_t)q * 2 + 1) * HS, sm);
    }
    gridbar(bar);
    // ---- phase C: logits + LSE + top-2 screening ----
    if (blk < NVT)
      logits_block(blk, tid, embbf, hshi + ((size_t)q * 2 + 1) * HS, gum_t, red, sm);
    gridbar(bar);
    // ---- phase D: final reduce + exact rescore + sample ----
    if (blk < BATCH)
      sample_block(blk, tid, t, red, emb, hbuf + HS, gum_t, xhi, xlo, out, sm);
    gridbar(bar);
  }
}

}  // namespace

extern "C" void kernel_launch(void* const* d_in, const int* in_sizes, int n_in,
                              void* d_out, int out_size, void* d_ws, size_t ws_size,
                              hipStream_t stream) {
  const float* img  = (const float*)d_in[0];
  const float* W_fh = (const float*)d_in[1];
  const float* b_fh = (const float*)d_in[2];
  const float* Wc   = (const float*)d_in[3];
  const float* bc   = (const float*)d_in[4];
  const float* Wh   = (const float*)d_in[5];
  const float* bh   = (const float*)d_in[6];
  const float* W_ih = (const float*)d_in[7];
  const float* W_hh = (const float*)d_in[8];
  const float* b_l  = (const float*)d_in[9];
  const float* emb  = (const float*)d_in[10];
  const float* gum  = (const float*)d_in[11];
  float* out = (float*)d_out;

  float* w     = (float*)d_ws;
  float* femb  = w;                                    // 3136*512
  float* fmean = femb + (size_t)3136 * 512;            // 64*512
  float* hbuf  = fmean + 64 * 512;                     // 2*64*512 f32
  float* cbuf  = hbuf + 2 * 64 * 512;                  // 2*64*512 f32
  float* red   = cbuf + 2 * 64 * 512;                  // 250*64*8
  unsigned* bar = (unsigned*)(red + 250 * 64 * 8);     // 8 uints

  unsigned short* us = (unsigned short*)(bar + 8);
  unsigned short* embbf  = us;                                  // 32000*512
  unsigned short* imghi  = embbf + (size_t)VOC * EMBN;          // 3136*2048
  unsigned short* imglo  = imghi + (size_t)3136 * 2048;
  unsigned short* wfh_hi = imglo + (size_t)3136 * 2048;         // 512*2048 (W_fh^T)
  unsigned short* wfh_lo = wfh_hi + (size_t)512 * 2048;
  unsigned short* wg     = wfh_lo + (size_t)512 * 2048;         // [l][mat][hi/lo][2048][512]
  const size_t WGM = (size_t)G4 * 512;
  unsigned short* xhi    = wg + 8 * WGM;                        // 64*512
  unsigned short* xlo    = xhi + 64 * 512;
  unsigned short* hshi   = xlo + 64 * 512;                      // [2 parity][2 layer][64][512]
  unsigned short* hslo   = hshi + (size_t)4 * 64 * 512;

  auto wgp = [&](int l, int mat, int part_) -> unsigned short* {
    return wg + (((size_t)l * 2 + mat) * 2 + part_) * WGM;
  };

  // ---- one-time prep ----
  k_emb2bf<<<8000, 256, 0, stream>>>(emb, embbf);
  k_split<<<3136 * 2048 / 8 / 256, 256, 0, stream>>>(img, imghi, imglo);
  k_trans<<<dim3(FEATN / 32, FHN / 32), 256, 0, stream>>>(W_fh, wfh_hi, wfh_lo, FEATN, FHN);
  for (int l = 0; l < 2; ++l) {
    k_trans<<<dim3(EMBN / 32, G4 / 32), 256, 0, stream>>>(W_ih + (size_t)l * EMBN * G4, wgp(l, 0, 0), wgp(l, 0, 1), EMBN, G4);
    k_trans<<<dim3(HID / 32, G4 / 32), 256, 0, stream>>>(W_hh + (size_t)l * HID * G4, wgp(l, 1, 0), wgp(l, 1, 1), HID, G4);
  }
  k_feat_mfma<<<dim3(49, 8), 256, 0, stream>>>(imghi, imglo, wfh_hi, wfh_lo, b_fh, femb);
  k_mean<<<128, 256, 0, stream>>>(femb, fmean);
  k_h0c0<<<dim3(8, 2, 2), 256, 0, stream>>>(fmean, Wc, bc, Wh, bh, hbuf, cbuf, hshi, hslo);
  k_initx<<<128, 256, 0, stream>>>(xhi, xlo);
  k_zero<<<1, 64, 0, stream>>>(bar);

  // ---- persistent 40-step decode (256 blocks, 1/CU forced by 84KB LDS) ----
  k_persist<<<NBLK, 256, 0, stream>>>(embbf, emb, gum, wg, b_l, hbuf, cbuf,
                                      xhi, xlo, hshi, hslo, red, out, bar);
}